// Round 4
// baseline (425.053 us; speedup 1.0000x reference)
//
#include <hip/hip_runtime.h>

// LIF feed-forward scan, T=256, B=64, N=4096, fp32 in/out.
// One thread owns 2 adjacent channels (float2), loops over t.
// Memory-bound: 512 MB total traffic -> ~81 us floor at 6.3 TB/s.
//
// Round-2 post-mortem: numerics bit-exact (absmax 0.0 on first check).
// 424 us came from 1 wave/SIMD occupancy (256 blocks) with no MLP.
// This version: float2/thread -> 512 blocks (2/CU, 8 waves/CU) and an
// explicit 16-deep load batch into statically-indexed registers so ~8 KB
// per wave of loads is in flight (Little's law needs ~9.2 KB per CU).

constexpr int T_STEPS = 256;
constexpr int BN      = 64 * 4096;   // elements per time step
constexpr int J2      = BN / 2;      // float2 groups per time step (131072)
constexpr int UNROLL  = 16;          // time steps batched per load group

// One LIF step, bit-exact vs numpy fp32 (no FMA contraction):
//   v_dec = v + 0.1f * ((0 - v) + i)    ((0-v)+i == i-v exactly)
//   i_dec = 0.8f * i                    (f32(1 - 0.001*200.0) == 0.8f)
//   z     = (v_dec - 1 > 0)  == (v_dec > 1.0f)  (Sterbenz-exact)
//   v     = z ? 0 : v_dec
//   i     = i_dec + x_t
#define LIF_STEP(V, I, XIN, ZOUT)                                         \
    {                                                                      \
        float vd = __fadd_rn((V), __fmul_rn(0.1f, __fsub_rn((I), (V))));   \
        float id = __fmul_rn(0.8f, (I));                                   \
        bool  s  = vd > 1.0f;                                              \
        (ZOUT) = s ? 1.0f : 0.0f;                                          \
        (V)    = s ? 0.0f : vd;                                            \
        (I)    = __fadd_rn(id, (XIN));                                     \
    }

__global__ __launch_bounds__(256) void lif_fwd(const float2* __restrict__ x,
                                               float2* __restrict__ out) {
    const int j = blockIdx.x * 256 + threadIdx.x;   // 0 .. J2-1
    const float2* xp = x + j;
    float2*       op = out + j;

    float v0 = 0.f, v1 = 0.f;   // membrane
    float c0 = 0.f, c1 = 0.f;   // synaptic current

    for (int tb = 0; tb < T_STEPS; tb += UNROLL) {
        // Issue all UNROLL loads before any use: addresses are independent
        // of the recurrence state, so these stay in flight together.
        // Fully-unrolled loops => xt[] is statically indexed (registers,
        // not scratch).
        float2 xt[UNROLL];
        #pragma unroll
        for (int u = 0; u < UNROLL; ++u)
            xt[u] = xp[(size_t)(tb + u) * J2];

        #pragma unroll
        for (int u = 0; u < UNROLL; ++u) {
            float2 z2;
            LIF_STEP(v0, c0, xt[u].x, z2.x);
            LIF_STEP(v1, c1, xt[u].y, z2.y);
            op[(size_t)(tb + u) * J2] = z2;
        }
    }
}

extern "C" void kernel_launch(void* const* d_in, const int* in_sizes, int n_in,
                              void* d_out, int out_size, void* d_ws, size_t ws_size,
                              hipStream_t stream) {
    const float2* x   = (const float2*)d_in[0];
    float2*       out = (float2*)d_out;
    // J2 = 131072 threads -> 512 blocks x 256 threads (2 blocks/CU, 8 waves/CU).
    lif_fwd<<<dim3(J2 / 256), dim3(256), 0, stream>>>(x, out);
}

// Round 5
// 411.832 us; speedup vs baseline: 1.0321x; 1.0321x over previous
//
#include <hip/hip_runtime.h>

// LIF feed-forward scan, T=256, B=64, N=4096, fp32 in/out.
// 512 MB total traffic -> ~81 us kernel floor at 6.3 TB/s.
//
// Round-4 post-mortem: float4/256blk/unroll8 (424us) == float2/512blk/
// batch16 (425us) to 0.2%; lif_fwd absent from rocprof top-5 while 166us
// fills are present. This version eliminates the remaining kernel-side
// suspects: (1) possible scratch demotion of the xt[] batch array (rule
// #20) -- now 8 NAMED f2 registers, no arrays; (2) load/compute phase
// gaps -- now a rotating software pipeline where each slot's reload
// issues immediately after its consume, so ~8 loads/wave (32KB/CU at 8
// waves/CU) are in flight continuously vs 9.2KB Little's-law need;
// (3) plain cached streams -- now nontemporal load+store (read-once /
// write-once data, keep L2 out of the path).

typedef float f2 __attribute__((ext_vector_type(2)));

constexpr int T_STEPS = 256;
constexpr int BN      = 64 * 4096;   // elements per time step
constexpr int J2      = BN / 2;      // f2 groups per time step (131072)
constexpr int DEPTH   = 8;           // pipeline depth (time steps in flight)

// One LIF step, bit-exact vs numpy fp32 (no FMA contraction) — validated
// absmax==0.0 in rounds 2/4:
//   v_dec = v + 0.1f * (i - v)     ((0-v)+i == i-v exactly)
//   i_dec = 0.8f * i               (f32(1 - 0.001*200.0) == 0.8f)
//   z     = (v_dec - 1 > 0) == (v_dec > 1.0f)   (sign-exact)
//   v     = z ? 0 : v_dec ;  i = i_dec + x_t
#define LIF_STEP(V, I, XIN, ZOUT)                                         \
    {                                                                      \
        float vd = __fadd_rn((V), __fmul_rn(0.1f, __fsub_rn((I), (V))));   \
        float id = __fmul_rn(0.8f, (I));                                   \
        bool  s  = vd > 1.0f;                                              \
        (ZOUT) = s ? 1.0f : 0.0f;                                          \
        (V)    = s ? 0.0f : vd;                                            \
        (I)    = __fadd_rn(id, (XIN));                                     \
    }

// Consume buffer B (time t), store its spikes, immediately reload B with
// time t+DEPTH. Loads stay 8-deep in flight at all times.
#define SLOT_MAIN(K, B)                                                    \
    {                                                                      \
        f2 zz;                                                             \
        LIF_STEP(v0, c0, (B).x, zz.x);                                     \
        LIF_STEP(v1, c1, (B).y, zz.y);                                     \
        __builtin_nontemporal_store(zz, os + (size_t)(K) * J2);            \
        (B) = __builtin_nontemporal_load(xl + (size_t)(K) * J2);           \
    }

#define SLOT_EPI(K, B)                                                     \
    {                                                                      \
        f2 zz;                                                             \
        LIF_STEP(v0, c0, (B).x, zz.x);                                     \
        LIF_STEP(v1, c1, (B).y, zz.y);                                     \
        __builtin_nontemporal_store(zz, os + (size_t)(K) * J2);            \
    }

__global__ __launch_bounds__(256) void lif_fwd(const f2* __restrict__ x,
                                               f2* __restrict__ out) {
    const int j = blockIdx.x * 256 + threadIdx.x;   // 0 .. J2-1
    const f2* xl = x + j;     // next-load pointer
    f2*       os = out + j;   // store pointer (current group base)

    float v0 = 0.f, v1 = 0.f;   // membrane
    float c0 = 0.f, c1 = 0.f;   // synaptic current

    // Prologue: fill the pipeline with t = 0..7. Named registers only —
    // no arrays, scratch demotion impossible.
    f2 b0 = __builtin_nontemporal_load(xl + (size_t)0 * J2);
    f2 b1 = __builtin_nontemporal_load(xl + (size_t)1 * J2);
    f2 b2 = __builtin_nontemporal_load(xl + (size_t)2 * J2);
    f2 b3 = __builtin_nontemporal_load(xl + (size_t)3 * J2);
    f2 b4 = __builtin_nontemporal_load(xl + (size_t)4 * J2);
    f2 b5 = __builtin_nontemporal_load(xl + (size_t)5 * J2);
    f2 b6 = __builtin_nontemporal_load(xl + (size_t)6 * J2);
    f2 b7 = __builtin_nontemporal_load(xl + (size_t)7 * J2);
    xl += (size_t)DEPTH * J2;

    // Main: 31 iterations, t = 0..247 consumed, t = 8..255 reloaded.
    for (int tb = 0; tb < T_STEPS - DEPTH; tb += DEPTH) {
        SLOT_MAIN(0, b0);
        SLOT_MAIN(1, b1);
        SLOT_MAIN(2, b2);
        SLOT_MAIN(3, b3);
        SLOT_MAIN(4, b4);
        SLOT_MAIN(5, b5);
        SLOT_MAIN(6, b6);
        SLOT_MAIN(7, b7);
        xl += (size_t)DEPTH * J2;
        os += (size_t)DEPTH * J2;
    }
    // Epilogue: t = 248..255, no reload.
    SLOT_EPI(0, b0);
    SLOT_EPI(1, b1);
    SLOT_EPI(2, b2);
    SLOT_EPI(3, b3);
    SLOT_EPI(4, b4);
    SLOT_EPI(5, b5);
    SLOT_EPI(6, b6);
    SLOT_EPI(7, b7);
}

extern "C" void kernel_launch(void* const* d_in, const int* in_sizes, int n_in,
                              void* d_out, int out_size, void* d_ws, size_t ws_size,
                              hipStream_t stream) {
    const f2* x   = (const f2*)d_in[0];
    f2*       out = (f2*)d_out;
    // J2 = 131072 threads -> 512 blocks x 256 threads (2 blocks/CU, 8 waves/CU).
    lif_fwd<<<dim3(J2 / 256), dim3(256), 0, stream>>>(x, out);
}